// Round 6
// baseline (1333.134 us; speedup 1.0000x reference)
//
#include <hip/hip_runtime.h>

typedef __attribute__((ext_vector_type(8))) short s16x8;
typedef __attribute__((ext_vector_type(4))) short s16x4;
typedef __attribute__((ext_vector_type(4))) float f32x4;

#define NTOK 49
#define CDIM 384
#define INNER 512
#define XW_STRIDE 408   // elems; 816B rows: bank = (12*l15+4*l4)%32 -> 2-way (free)
#define PL_STRIDE 88    // elems; 176B rows: 2-way

__device__ __forceinline__ short f2bf(float f) {
  unsigned u = __float_as_uint(f);
  u += 0x7fffu + ((u >> 16) & 1u);   // RNE
  return (short)(u >> 16);
}

__device__ __forceinline__ f32x4 mfma16(s16x8 a, s16x8 b, f32x4 c) {
  return __builtin_amdgcn_mfma_f32_16x16x32_bf16(a, b, c, 0, 0, 0);
}

// ---------------- kernel 0: weight transpose->bf16 + bias matrix ----------------
__global__ void prep_kernel(const float* __restrict__ w_qkv, const float* __restrict__ w_out,
                            const float* __restrict__ bias_table,
                            short* __restrict__ wqkvT, short* __restrict__ woutT,
                            float* __restrict__ biasm) {
  int i = blockIdx.x * 256 + threadIdx.x;
  if (i < 1536 * CDIM) {
    int col = i % 1536, k = i / 1536;  // coalesced read over col
    wqkvT[(size_t)col * CDIM + k] = f2bf(w_qkv[(size_t)k * 1536 + col]);
  } else if (i < 1536 * CDIM + CDIM * INNER) {
    int j = i - 1536 * CDIM;
    int c = j % CDIM, ii = j / CDIM;   // coalesced read over c
    woutT[(size_t)c * INNER + ii] = f2bf(w_out[(size_t)ii * CDIM + c]);
  } else if (i < 1536 * CDIM + CDIM * INNER + 8 * NTOK * NTOK) {
    int j = i - 1536 * CDIM - CDIM * INNER;
    int h = j / 2401, t = j % 2401;
    int m = t / 49, n = t % 49;
    int rel = (m / 7 - n / 7 + 6) * 13 + (m % 7 - n % 7 + 6);
    biasm[j] = bias_table[rel * 8 + h];
  }
}

// ---------------- kernel 1: fused window-partition + QKV projection ----------------
// block = 1 window, 512 thr (8 waves = 8 heads); col-tile t in {q,k,v}
__global__ __launch_bounds__(512, 1) void qkv_kernel(
    const float* __restrict__ x, const float* __restrict__ b_qkv,
    const short* __restrict__ wqkvT,
    short* __restrict__ qs, short* __restrict__ ks, short* __restrict__ vs) {
  __shared__ short xw[64 * XW_STRIDE];
  const int win = blockIdx.x;
  const int b = win >> 6, r1 = (win >> 3) & 7, r2 = win & 7;
  const int tid = threadIdx.x;
  const float* xb = x + (size_t)b * CDIM * 3136 + (r1 * 7) * 56 + (r2 * 7);
  // stage: lane = token (7-float contiguous runs in x), loop channels
  {
    const int mm = tid & 63;
    const int c0 = tid >> 6;
    int xoff = -1;
    if (mm < NTOK) xoff = (mm / 7) * 56 + (mm % 7);
    for (int it = 0; it < 48; ++it) {
      int c = c0 + it * 8;
      float v = (xoff >= 0) ? xb[(size_t)c * 3136 + xoff] : 0.f;
      xw[mm * XW_STRIDE + c] = f2bf(v);
    }
  }
  __syncthreads();
  const int wave = tid >> 6, lane = tid & 63;
  const int l15 = lane & 15, l4 = lane >> 4;
  const size_t hb = (size_t)win * 8 + wave;
  for (int tile = 0; tile < 3; ++tile) {
    f32x4 acc[4][4];
#pragma unroll
    for (int fm = 0; fm < 4; ++fm)
#pragma unroll
      for (int fn = 0; fn < 4; ++fn) acc[fm][fn] = (f32x4){0.f, 0.f, 0.f, 0.f};
    const short* wb = wqkvT + ((size_t)tile * 512 + wave * 64) * CDIM;
    for (int kk = 0; kk < 12; ++kk) {
      s16x8 av[4], bv[4];
#pragma unroll
      for (int fm = 0; fm < 4; ++fm)
        av[fm] = *(const s16x8*)(&xw[(fm * 16 + l15) * XW_STRIDE + kk * 32 + l4 * 8]);
#pragma unroll
      for (int fn = 0; fn < 4; ++fn)
        bv[fn] = *(const s16x8*)(wb + (size_t)(fn * 16 + l15) * CDIM + kk * 32 + l4 * 8);
#pragma unroll
      for (int fm = 0; fm < 4; ++fm)
#pragma unroll
        for (int fn = 0; fn < 4; ++fn)
          acc[fm][fn] = mfma16(av[fm], bv[fn], acc[fm][fn]);
    }
    float bq[4];
#pragma unroll
    for (int fn = 0; fn < 4; ++fn)
      bq[fn] = b_qkv[tile * 512 + wave * 64 + fn * 16 + l15];
    if (tile < 2) {
      short* dst = (tile == 0 ? qs : ks) + hb * (NTOK * 64);
      const float scl = (tile == 0) ? 0.125f : 1.f;
#pragma unroll
      for (int fm = 0; fm < 4; ++fm)
#pragma unroll
        for (int j = 0; j < 4; ++j) {
          int m = fm * 16 + l4 * 4 + j;
          if (m < NTOK) {
#pragma unroll
            for (int fn = 0; fn < 4; ++fn)
              dst[m * 64 + fn * 16 + l15] = f2bf((acc[fm][fn][j] + bq[fn]) * scl);
          }
        }
    } else {  // v: store transposed [d][token], packed b64 over 4 consecutive tokens
      short* dst = vs + hb * 4096;
#pragma unroll
      for (int fm = 0; fm < 4; ++fm) {
        int bm = fm * 16 + l4 * 4;
#pragma unroll
        for (int fn = 0; fn < 4; ++fn) {
          int d = fn * 16 + l15;
          if (bm + 3 < NTOK) {
            s16x4 pk;
#pragma unroll
            for (int j = 0; j < 4; ++j) pk[j] = f2bf(acc[fm][fn][j] + bq[fn]);
            *(s16x4*)(dst + d * 64 + bm) = pk;
          } else if (bm < NTOK) {
#pragma unroll
            for (int j = 0; j < 4; ++j)
              if (bm + j < NTOK) dst[d * 64 + bm + j] = f2bf(acc[fm][fn][j] + bq[fn]);
          }
        }
      }
    }
  }
}

// ---------------- kernel 2: attention per (window, head), 1 wave ----------------
__global__ __launch_bounds__(64) void attn_kernel(
    const short* __restrict__ qs, const short* __restrict__ ks, const short* __restrict__ vs,
    const float* __restrict__ biasm, float* __restrict__ attn_out, short* __restrict__ os) {
  __shared__ short pl[64 * PL_STRIDE];
  const int blk = blockIdx.x;
  const int win = blk >> 3, h = blk & 7;
  const int lane = threadIdx.x;
  const int l15 = lane & 15, l4 = lane >> 4;
  const short* qb = qs + (size_t)blk * (NTOK * 64);
  const short* kb = ks + (size_t)blk * (NTOK * 64);
  f32x4 acc[4][4];
#pragma unroll
  for (int fm = 0; fm < 4; ++fm)
#pragma unroll
    for (int fn = 0; fn < 4; ++fn) acc[fm][fn] = (f32x4){0.f, 0.f, 0.f, 0.f};
#pragma unroll
  for (int kk = 0; kk < 2; ++kk) {
    s16x8 av[4], bv[4];
#pragma unroll
    for (int fm = 0; fm < 4; ++fm)
      av[fm] = *(const s16x8*)(qb + (fm * 16 + l15) * 64 + kk * 32 + l4 * 8);
#pragma unroll
    for (int fn = 0; fn < 4; ++fn)
      bv[fn] = *(const s16x8*)(kb + (fn * 16 + l15) * 64 + kk * 32 + l4 * 8);
#pragma unroll
    for (int fm = 0; fm < 4; ++fm)
#pragma unroll
      for (int fn = 0; fn < 4; ++fn)
        acc[fm][fn] = mfma16(av[fm], bv[fn], acc[fm][fn]);
  }
  const float* bh = biasm + h * 2401;
  float* ao = attn_out + (size_t)blk * (NTOK * NTOK);
#pragma unroll
  for (int fm = 0; fm < 4; ++fm) {
#pragma unroll
    for (int j = 0; j < 4; ++j) {
      const int m = fm * 16 + l4 * 4 + j;
      const bool mok = (m < NTOK);
      float sv[4], p[4];
#pragma unroll
      for (int fn = 0; fn < 4; ++fn) {
        int n = fn * 16 + l15;
        float bias = (mok && n < NTOK) ? bh[m * 49 + n] : 0.f;
        sv[fn] = acc[fm][fn][j] + bias;
      }
      float mx = -1e30f;
#pragma unroll
      for (int fn = 0; fn < 4; ++fn)
        if (fn * 16 + l15 < NTOK) mx = fmaxf(mx, sv[fn]);
      mx = fmaxf(mx, __shfl_xor(mx, 1));
      mx = fmaxf(mx, __shfl_xor(mx, 2));
      mx = fmaxf(mx, __shfl_xor(mx, 4));
      mx = fmaxf(mx, __shfl_xor(mx, 8));
      float sum = 0.f;
#pragma unroll
      for (int fn = 0; fn < 4; ++fn) {
        int n = fn * 16 + l15;
        p[fn] = (n < NTOK) ? __expf(sv[fn] - mx) : 0.f;
        sum += p[fn];
      }
      sum += __shfl_xor(sum, 1);
      sum += __shfl_xor(sum, 2);
      sum += __shfl_xor(sum, 4);
      sum += __shfl_xor(sum, 8);
      const float inv = 1.f / sum;
#pragma unroll
      for (int fn = 0; fn < 4; ++fn) {
        int n = fn * 16 + l15;
        float pv = p[fn] * inv;
        if (mok && n < NTOK) ao[m * 49 + n] = pv;
        pl[m * PL_STRIDE + n] = f2bf(pv);   // pad cols exactly 0 -> PV safe
      }
    }
  }
  __syncthreads();
  const short* vb = vs + (size_t)blk * 4096;
  f32x4 oacc[4][4];
#pragma unroll
  for (int fm = 0; fm < 4; ++fm)
#pragma unroll
    for (int fn = 0; fn < 4; ++fn) oacc[fm][fn] = (f32x4){0.f, 0.f, 0.f, 0.f};
#pragma unroll
  for (int kk = 0; kk < 2; ++kk) {
    s16x8 av[4], bv[4];
#pragma unroll
    for (int fm = 0; fm < 4; ++fm)
      av[fm] = *(const s16x8*)(&pl[(fm * 16 + l15) * PL_STRIDE + kk * 32 + l4 * 8]);
#pragma unroll
    for (int fn = 0; fn < 4; ++fn)
      bv[fn] = *(const s16x8*)(vb + (fn * 16 + l15) * 64 + kk * 32 + l4 * 8);
#pragma unroll
    for (int fm = 0; fm < 4; ++fm)
#pragma unroll
      for (int fn = 0; fn < 4; ++fn)
        oacc[fm][fn] = mfma16(av[fm], bv[fn], oacc[fm][fn]);
  }
  short* ob = os + (size_t)win * (NTOK * INNER) + h * 64;
#pragma unroll
  for (int fm = 0; fm < 4; ++fm)
#pragma unroll
    for (int j = 0; j < 4; ++j) {
      int m = fm * 16 + l4 * 4 + j;
      if (m < NTOK) {
#pragma unroll
        for (int fn = 0; fn < 4; ++fn)
          ob[m * INNER + fn * 16 + l15] = f2bf(oacc[fm][fn][j]);
      }
    }
}

// ---------------- kernel 3: output projection + reverse window partition ----------------
__global__ __launch_bounds__(384, 1) void oproj_kernel(
    const short* __restrict__ os, const short* __restrict__ woutT,
    const float* __restrict__ b_out, float* __restrict__ outp) {
  __shared__ float ot[CDIM * 57];
  const int win = blockIdx.x;
  const int b = win >> 6, r1 = (win >> 3) & 7, r2 = win & 7;
  const int tid = threadIdx.x;
  const int wave = tid >> 6, lane = tid & 63;
  const int l15 = lane & 15, l4 = lane >> 4;
  const short* ab = os + (size_t)win * (NTOK * INNER);
  const short* bb = woutT + (size_t)wave * 64 * INNER;
  f32x4 acc[4][4];
#pragma unroll
  for (int fm = 0; fm < 4; ++fm)
#pragma unroll
    for (int fn = 0; fn < 4; ++fn) acc[fm][fn] = (f32x4){0.f, 0.f, 0.f, 0.f};
  for (int kk = 0; kk < 16; ++kk) {
    s16x8 av[4], bv[4];
#pragma unroll
    for (int fm = 0; fm < 4; ++fm)
      av[fm] = *(const s16x8*)(ab + (size_t)(fm * 16 + l15) * INNER + kk * 32 + l4 * 8);
#pragma unroll
    for (int fn = 0; fn < 4; ++fn)
      bv[fn] = *(const s16x8*)(bb + (size_t)(fn * 16 + l15) * INNER + kk * 32 + l4 * 8);
#pragma unroll
    for (int fm = 0; fm < 4; ++fm)
#pragma unroll
      for (int fn = 0; fn < 4; ++fn)
        acc[fm][fn] = mfma16(av[fm], bv[fn], acc[fm][fn]);
  }
  float bo[4];
#pragma unroll
  for (int fn = 0; fn < 4; ++fn) bo[fn] = b_out[wave * 64 + fn * 16 + l15];
#pragma unroll
  for (int fm = 0; fm < 4; ++fm)
#pragma unroll
    for (int j = 0; j < 4; ++j) {
      int m = fm * 16 + l4 * 4 + j;
      if (m < NTOK) {
#pragma unroll
        for (int fn = 0; fn < 4; ++fn)
          ot[(wave * 64 + fn * 16 + l15) * 57 + m] = acc[fm][fn][j] + bo[fn];
      }
    }
  __syncthreads();
  float* ob = outp + ((size_t)b * CDIM) * 3136 + (r1 * 7) * 56 + (r2 * 7);
  for (int i = tid; i < CDIM * 7; i += 384) {
    int c = i % CDIM;   // == tid
    int h1 = i / CDIM;
    float* dst = ob + (size_t)c * 3136 + h1 * 56;
    const float* src = &ot[c * 57 + h1 * 7];
#pragma unroll
    for (int w1 = 0; w1 < 7; ++w1) dst[w1] = src[w1];
  }
}

extern "C" void kernel_launch(void* const* d_in, const int* in_sizes, int n_in,
                              void* d_out, int out_size, void* d_ws, size_t ws_size,
                              hipStream_t stream) {
  const float* x          = (const float*)d_in[0];
  const float* w_qkv      = (const float*)d_in[1];
  const float* b_qkv      = (const float*)d_in[2];
  const float* w_out      = (const float*)d_in[3];
  const float* b_out      = (const float*)d_in[4];
  const float* bias_table = (const float*)d_in[5];

  // ws layout (all 16B-aligned):
  //   wqkvT bf16 [1536][384]            @ 0          (1,179,648)
  //   woutT bf16 [384][512]             @ 1,179,648  (393,216)
  //   biasm f32  [8][49][49]            @ 1,572,864  (76,832)
  //   ks bf16 [2048*8][49][64]          @ 2,097,152  (102,760,448)
  //   vs bf16 [2048*8][64][64] (v^T)    @ 104,857,600 (134,217,728)
  //   os bf16 [2048][49][512]           @ 239,075,328 (102,760,448) + 32KB tail pad
  // qs bf16 [2048*8][49][64] lives in d_out's `out` region (102.7MB of 154.1MB):
  //   written by qkv_kernel, read by attn_kernel, then oproj_kernel fully
  //   overwrites the region with the real output (stream-ordered). attn_kernel's
  //   d_out writes go to the disjoint `attn` region.
  const size_t NEED = 239075328ull + 102760448ull + 32768ull;  // ~342 MB
  if (ws_size < NEED) return;  // sentinel: absmax stays at 0.130859 -> ws too small

  char* ws = (char*)d_ws;
  short* wqkvT = (short*)(ws + 0);
  short* woutT = (short*)(ws + 1179648);
  float* biasm = (float*)(ws + 1572864);
  short* ks    = (short*)(ws + 2097152);
  short* vs    = (short*)(ws + 104857600);
  short* os    = (short*)(ws + 239075328);

  float* outp = (float*)d_out;
  float* attn = outp + (size_t)32 * CDIM * 3136;  // 38,535,168 floats
  short* qs   = (short*)outp;                     // scratch alias, see comment above

  prep_kernel<<<3148, 256, 0, stream>>>(w_qkv, w_out, bias_table, wqkvT, woutT, biasm);
  qkv_kernel<<<2048, 512, 0, stream>>>(x, b_qkv, wqkvT, qs, ks, vs);
  attn_kernel<<<16384, 64, 0, stream>>>(qs, ks, vs, biasm, attn, os);
  oproj_kernel<<<2048, 384, 0, stream>>>(os, woutT, b_out, outp);
}

// Round 9
// 1160.826 us; speedup vs baseline: 1.1484x; 1.1484x over previous
//
#include <hip/hip_runtime.h>

typedef __attribute__((ext_vector_type(8))) short s16x8;
typedef __attribute__((ext_vector_type(4))) short s16x4;
typedef __attribute__((ext_vector_type(4))) float f32x4;

#define NTOK 49
#define CDIM 384
#define INNER 512
#define PL_STRIDE 88    // elems; 176B rows: 2-way
#define XS_STRIDE 392   // elems; 784B rows (16B-mult); staging writes 8-way (accepted)
#define VT_STRIDE 72    // elems; 144B rows (16B-mult)

__device__ __forceinline__ short f2bf(float f) {
  unsigned u = __float_as_uint(f);
  u += 0x7fffu + ((u >> 16) & 1u);   // RNE
  return (short)(u >> 16);
}

__device__ __forceinline__ f32x4 mfma16(s16x8 a, s16x8 b, f32x4 c) {
  return __builtin_amdgcn_mfma_f32_16x16x32_bf16(a, b, c, 0, 0, 0);
}

// ---------------- kernel 0: weight transpose->bf16 + bias matrix ----------------
__global__ void prep_kernel(const float* __restrict__ w_qkv, const float* __restrict__ w_out,
                            const float* __restrict__ bias_table,
                            short* __restrict__ wqkvT, short* __restrict__ woutT,
                            float* __restrict__ biasm) {
  int i = blockIdx.x * 256 + threadIdx.x;
  if (i < 1536 * CDIM) {
    int col = i % 1536, k = i / 1536;  // coalesced read over col
    wqkvT[(size_t)col * CDIM + k] = f2bf(w_qkv[(size_t)k * 1536 + col]);
  } else if (i < 1536 * CDIM + CDIM * INNER) {
    int j = i - 1536 * CDIM;
    int c = j % CDIM, ii = j / CDIM;   // coalesced read over c
    woutT[(size_t)c * INNER + ii] = f2bf(w_out[(size_t)ii * CDIM + c]);
  } else if (i < 1536 * CDIM + CDIM * INNER + 8 * NTOK * NTOK) {
    int j = i - 1536 * CDIM - CDIM * INNER;
    int h = j / 2401, t = j % 2401;
    int m = t / 49, n = t % 49;
    int rel = (m / 7 - n / 7 + 6) * 13 + (m % 7 - n % 7 + 6);
    biasm[j] = bias_table[rel * 8 + h];
  }
}

// ---------------- kernel 1: flat-M QKV GEMM ----------------
// M = 100352 flat tokens (784 m-blocks x 128 rows, exact), N-block in {q,k,v}.
// Window partition applied at STORE time only. x staged coalesced (392
// contiguous floats per (b,r1) group per channel). Grid 2352 = 784*3,
// XCD-swizzled so the 3 n-siblings (same x rows) share an XCD's L2.
__global__ __launch_bounds__(512, 2) void qkv2_kernel(
    const float* __restrict__ x, const float* __restrict__ b_qkv,
    const short* __restrict__ wqkvT,
    short* __restrict__ qs, short* __restrict__ ks, short* __restrict__ vs) {
  __shared__ short xs[128 * XS_STRIDE];  // 100,352 B (gfx950 allows >64KB)
  const int bid = blockIdx.x;
  const int logical = (bid & 7) * 294 + (bid >> 3);  // bijective: 2352 = 8*294
  const int nb = logical % 3;   // 0=q 1=k 2=v
  const int mb = logical / 3;   // 0..783
  const int m0 = mb * 128;
  const int tid = threadIdx.x;

  // ---- stage: thread = row (tid&127), c-phase (tid>>7); coalesced 256B runs ----
  {
    const int r = tid & 127, c0 = tid >> 7;
    const int mrow = m0 + r;
    const int g = mrow / 392, p = mrow - g * 392;   // g = (b, r1) group
    const float* xr = x + (size_t)(g >> 3) * (CDIM * 3136) + (g & 7) * 392 + p;
    short* drow = &xs[r * XS_STRIDE];
#pragma unroll 8
    for (int it = 0; it < 96; ++it) {
      int c = c0 + it * 4;
      drow[c] = f2bf(xr[(size_t)c * 3136]);
    }
  }
  __syncthreads();

  const int wave = tid >> 6, lane = tid & 63;
  const int l15 = lane & 15, l4 = lane >> 4;
  const int wr = wave >> 2, wc = wave & 3;   // 2 (m) x 4 (n) waves
  f32x4 acc[4][8];
#pragma unroll
  for (int fm = 0; fm < 4; ++fm)
#pragma unroll
    for (int fn = 0; fn < 8; ++fn) acc[fm][fn] = (f32x4){0.f, 0.f, 0.f, 0.f};

  const short* wbase = wqkvT + ((size_t)nb * 512 + wc * 128 + l15) * CDIM;
  for (int kk = 0; kk < 12; ++kk) {
    s16x8 av[4];
#pragma unroll
    for (int fm = 0; fm < 4; ++fm)
      av[fm] = *(const s16x8*)&xs[(wr * 64 + fm * 16 + l15) * XS_STRIDE + kk * 32 + l4 * 8];
#pragma unroll
    for (int fn = 0; fn < 8; ++fn) {
      s16x8 bv = *(const s16x8*)(wbase + (size_t)fn * 16 * CDIM + kk * 32 + l4 * 8);
#pragma unroll
      for (int fm = 0; fm < 4; ++fm)
        acc[fm][fn] = mfma16(av[fm], bv, acc[fm][fn]);
    }
  }

  // ---- epilogue: bias, scale(q), window-mapped store (32B-contiguous runs) ----
  float bq[8];
#pragma unroll
  for (int fn = 0; fn < 8; ++fn) bq[fn] = b_qkv[nb * 512 + wc * 128 + fn * 16 + l15];
  const float scl = (nb == 0) ? 0.125f : 1.f;
  short* dstt = (nb == 0) ? qs : (nb == 1 ? ks : vs);
#pragma unroll
  for (int fm = 0; fm < 4; ++fm) {
#pragma unroll
    for (int j = 0; j < 4; ++j) {
      const int mrow = m0 + wr * 64 + fm * 16 + l4 * 4 + j;
      const int g = mrow / 392, p = mrow - g * 392;
      const int h1 = p / 56, xcol = p - h1 * 56;
      const int r2 = xcol / 7, w1 = xcol - r2 * 7;
      const size_t rowbase = (size_t)((g * 8 + r2) * 8) * 3136 + (h1 * 7 + w1) * 64;
#pragma unroll
      for (int fn = 0; fn < 8; ++fn) {
        const int h = wc * 2 + (fn >> 2);
        const int d = ((fn & 3) << 4) + l15;
        dstt[rowbase + (size_t)h * 3136 + d] = f2bf((acc[fm][fn][j] + bq[fn]) * scl);
      }
    }
  }
}

// ---------------- kernel 2: attention per (window, head), 1 wave ----------------
// v now arrives UNtransposed ([tok][64], same as k); transpose into LDS here.
__global__ __launch_bounds__(64) void attn_kernel(
    const short* __restrict__ qs, const short* __restrict__ ks, const short* __restrict__ vs,
    const float* __restrict__ biasm, float* __restrict__ attn_out, short* __restrict__ os) {
  __shared__ short pl[64 * PL_STRIDE];
  __shared__ short vT[64 * VT_STRIDE];
  const int blk = blockIdx.x;
  const int win = blk >> 3, h = blk & 7;
  const int lane = threadIdx.x;
  const int l15 = lane & 15, l4 = lane >> 4;
  const short* qb = qs + (size_t)blk * (NTOK * 64);
  const short* kb = ks + (size_t)blk * (NTOK * 64);
  const short* vb = vs + (size_t)blk * (NTOK * 64);
  // V transpose: [tok][d] -> vT[d][tok]; zero pad toks so PV pads are clean
  {
    short* vrow = &vT[lane * VT_STRIDE];
    for (int t = 0; t < NTOK; ++t) vrow[t] = vb[t * 64 + lane];  // 128B coalesced loads
#pragma unroll
    for (int t = NTOK; t < 64; ++t) vrow[t] = 0;
  }
  f32x4 acc[4][4];
#pragma unroll
  for (int fm = 0; fm < 4; ++fm)
#pragma unroll
    for (int fn = 0; fn < 4; ++fn) acc[fm][fn] = (f32x4){0.f, 0.f, 0.f, 0.f};
#pragma unroll
  for (int kk = 0; kk < 2; ++kk) {
    s16x8 av[4], bv[4];
#pragma unroll
    for (int fm = 0; fm < 4; ++fm)
      av[fm] = *(const s16x8*)(qb + (fm * 16 + l15) * 64 + kk * 32 + l4 * 8);
#pragma unroll
    for (int fn = 0; fn < 4; ++fn)
      bv[fn] = *(const s16x8*)(kb + (fn * 16 + l15) * 64 + kk * 32 + l4 * 8);
#pragma unroll
    for (int fm = 0; fm < 4; ++fm)
#pragma unroll
      for (int fn = 0; fn < 4; ++fn)
        acc[fm][fn] = mfma16(av[fm], bv[fn], acc[fm][fn]);
  }
  const float* bh = biasm + h * 2401;
  float* ao = attn_out + (size_t)blk * (NTOK * NTOK);
#pragma unroll
  for (int fm = 0; fm < 4; ++fm) {
#pragma unroll
    for (int j = 0; j < 4; ++j) {
      const int m = fm * 16 + l4 * 4 + j;
      const bool mok = (m < NTOK);
      float sv[4], p[4];
#pragma unroll
      for (int fn = 0; fn < 4; ++fn) {
        int n = fn * 16 + l15;
        float bias = (mok && n < NTOK) ? bh[m * 49 + n] : 0.f;
        sv[fn] = acc[fm][fn][j] + bias;
      }
      float mx = -1e30f;
#pragma unroll
      for (int fn = 0; fn < 4; ++fn)
        if (fn * 16 + l15 < NTOK) mx = fmaxf(mx, sv[fn]);
      mx = fmaxf(mx, __shfl_xor(mx, 1));
      mx = fmaxf(mx, __shfl_xor(mx, 2));
      mx = fmaxf(mx, __shfl_xor(mx, 4));
      mx = fmaxf(mx, __shfl_xor(mx, 8));
      float sum = 0.f;
#pragma unroll
      for (int fn = 0; fn < 4; ++fn) {
        int n = fn * 16 + l15;
        p[fn] = (n < NTOK) ? __expf(sv[fn] - mx) : 0.f;
        sum += p[fn];
      }
      sum += __shfl_xor(sum, 1);
      sum += __shfl_xor(sum, 2);
      sum += __shfl_xor(sum, 4);
      sum += __shfl_xor(sum, 8);
      const float inv = 1.f / sum;
#pragma unroll
      for (int fn = 0; fn < 4; ++fn) {
        int n = fn * 16 + l15;
        float pv = p[fn] * inv;
        if (mok && n < NTOK) ao[m * 49 + n] = pv;
        pl[m * PL_STRIDE + n] = f2bf(pv);   // pad cols exactly 0 -> PV safe
      }
    }
  }
  __syncthreads();  // covers pl and vT writes
  f32x4 oacc[4][4];
#pragma unroll
  for (int fm = 0; fm < 4; ++fm)
#pragma unroll
    for (int fn = 0; fn < 4; ++fn) oacc[fm][fn] = (f32x4){0.f, 0.f, 0.f, 0.f};
#pragma unroll
  for (int kk = 0; kk < 2; ++kk) {
    s16x8 av[4], bv[4];
#pragma unroll
    for (int fm = 0; fm < 4; ++fm)
      av[fm] = *(const s16x8*)(&pl[(fm * 16 + l15) * PL_STRIDE + kk * 32 + l4 * 8]);
#pragma unroll
    for (int fn = 0; fn < 4; ++fn)
      bv[fn] = *(const s16x8*)(&vT[(fn * 16 + l15) * VT_STRIDE + kk * 32 + l4 * 8]);
#pragma unroll
    for (int fm = 0; fm < 4; ++fm)
#pragma unroll
      for (int fn = 0; fn < 4; ++fn)
        oacc[fm][fn] = mfma16(av[fm], bv[fn], oacc[fm][fn]);
  }
  short* ob = os + (size_t)win * (NTOK * INNER) + h * 64;
#pragma unroll
  for (int fm = 0; fm < 4; ++fm)
#pragma unroll
    for (int j = 0; j < 4; ++j) {
      int m = fm * 16 + l4 * 4 + j;
      if (m < NTOK) {
#pragma unroll
        for (int fn = 0; fn < 4; ++fn)
          ob[m * INNER + fn * 16 + l15] = f2bf(oacc[fm][fn][j]);
      }
    }
}

// ---------------- kernel 3: output projection + reverse window partition ----------------
__global__ __launch_bounds__(384, 1) void oproj_kernel(
    const short* __restrict__ os, const short* __restrict__ woutT,
    const float* __restrict__ b_out, float* __restrict__ outp) {
  __shared__ float ot[CDIM * 57];
  const int win = blockIdx.x;
  const int b = win >> 6, r1 = (win >> 3) & 7, r2 = win & 7;
  const int tid = threadIdx.x;
  const int wave = tid >> 6, lane = tid & 63;
  const int l15 = lane & 15, l4 = lane >> 4;
  const short* ab = os + (size_t)win * (NTOK * INNER);
  const short* bb = woutT + (size_t)wave * 64 * INNER;
  f32x4 acc[4][4];
#pragma unroll
  for (int fm = 0; fm < 4; ++fm)
#pragma unroll
    for (int fn = 0; fn < 4; ++fn) acc[fm][fn] = (f32x4){0.f, 0.f, 0.f, 0.f};
  for (int kk = 0; kk < 16; ++kk) {
    s16x8 av[4], bv[4];
#pragma unroll
    for (int fm = 0; fm < 4; ++fm)
      av[fm] = *(const s16x8*)(ab + (size_t)(fm * 16 + l15) * INNER + kk * 32 + l4 * 8);
#pragma unroll
    for (int fn = 0; fn < 4; ++fn)
      bv[fn] = *(const s16x8*)(bb + (size_t)(fn * 16 + l15) * INNER + kk * 32 + l4 * 8);
#pragma unroll
    for (int fm = 0; fm < 4; ++fm)
#pragma unroll
      for (int fn = 0; fn < 4; ++fn)
        acc[fm][fn] = mfma16(av[fm], bv[fn], acc[fm][fn]);
  }
  float bo[4];
#pragma unroll
  for (int fn = 0; fn < 4; ++fn) bo[fn] = b_out[wave * 64 + fn * 16 + l15];
#pragma unroll
  for (int fm = 0; fm < 4; ++fm)
#pragma unroll
    for (int j = 0; j < 4; ++j) {
      int m = fm * 16 + l4 * 4 + j;
      if (m < NTOK) {
#pragma unroll
        for (int fn = 0; fn < 4; ++fn)
          ot[(wave * 64 + fn * 16 + l15) * 57 + m] = acc[fm][fn][j] + bo[fn];
      }
    }
  __syncthreads();
  float* ob = outp + ((size_t)b * CDIM) * 3136 + (r1 * 7) * 56 + (r2 * 7);
  for (int i = tid; i < CDIM * 7; i += 384) {
    int c = i % CDIM;   // == tid
    int h1 = i / CDIM;
    float* dst = ob + (size_t)c * 3136 + h1 * 56;
    const float* src = &ot[c * 57 + h1 * 7];
#pragma unroll
    for (int w1 = 0; w1 < 7; ++w1) dst[w1] = src[w1];
  }
}

extern "C" void kernel_launch(void* const* d_in, const int* in_sizes, int n_in,
                              void* d_out, int out_size, void* d_ws, size_t ws_size,
                              hipStream_t stream) {
  const float* x          = (const float*)d_in[0];
  const float* w_qkv      = (const float*)d_in[1];
  const float* b_qkv      = (const float*)d_in[2];
  const float* w_out      = (const float*)d_in[3];
  const float* b_out      = (const float*)d_in[4];
  const float* bias_table = (const float*)d_in[5];

  // ws layout (all 16B-aligned):
  //   wqkvT bf16 [1536][384]            @ 0            (1,179,648)
  //   woutT bf16 [384][512]             @ 1,179,648    (393,216)
  //   biasm f32  [8][49][49]            @ 1,572,864    (76,832)
  //   ks bf16 [2048*8][49][64]          @ 2,097,152    (102,760,448)
  //   vs bf16 [2048*8][49][64]          @ 104,857,600  (102,760,448)  (UNtransposed now)
  //   os bf16 [2048][49][512]           @ 207,618,048  (102,760,448) + 32KB pad
  // qs bf16 [2048*8][49][64] lives in d_out's `out` region (102.7MB of 154.1MB):
  //   written by qkv2_kernel, read by attn_kernel, then oproj_kernel fully
  //   overwrites the region (stream-ordered). attn's d_out writes go to the
  //   disjoint `attn` region.
  const size_t NEED = 207618048ull + 102760448ull + 32768ull;  // ~296 MB
  if (ws_size < NEED) return;  // sentinel: absmax stays at 0.130859 -> ws too small

  char* ws = (char*)d_ws;
  short* wqkvT = (short*)(ws + 0);
  short* woutT = (short*)(ws + 1179648);
  float* biasm = (float*)(ws + 1572864);
  short* ks    = (short*)(ws + 2097152);
  short* vs    = (short*)(ws + 104857600);
  short* os    = (short*)(ws + 207618048);

  float* outp = (float*)d_out;
  float* attn = outp + (size_t)32 * CDIM * 3136;  // 38,535,168 floats
  short* qs   = (short*)outp;                     // scratch alias, see comment above

  prep_kernel<<<3148, 256, 0, stream>>>(w_qkv, w_out, bias_table, wqkvT, woutT, biasm);
  qkv2_kernel<<<2352, 512, 0, stream>>>(x, b_qkv, wqkvT, qs, ks, vs);
  attn_kernel<<<16384, 64, 0, stream>>>(qs, ks, vs, biasm, attn, os);
  oproj_kernel<<<2048, 384, 0, stream>>>(os, woutT, b_out, outp);
}